// Round 5
// baseline (552.583 us; speedup 1.0000x reference)
//
#include <hip/hip_runtime.h>
#include <hip/hip_bf16.h>
#include <cstdint>
#include <cstddef>

using u16 = unsigned short;
using u32 = unsigned int;

typedef float f32x4 __attribute__((ext_vector_type(4)));
typedef short s16x8 __attribute__((ext_vector_type(8)));
typedef _Float16 f16x8 __attribute__((ext_vector_type(8)));
typedef unsigned short u16x4 __attribute__((ext_vector_type(4)));
typedef u32 u32x4 __attribute__((ext_vector_type(4)));

constexpr int Bc  = 2;
constexpr int Sc  = 2048;
constexpr int Dc  = 1024;
constexpr int Hc  = 16;
constexpr int DKc = 64;
constexpr int BHc = Bc * Hc;        // 32
constexpr int NREL = 257;           // 2*128+1
constexpr int RKROWS = 272;         // rel_k rows padded to 17*16
constexpr int RVCOLS = 288;         // rel_v^T cols padded to 9*32

// scores in exp2-units: Q pre-scaled by 0.125*log2(e) at projection.
constexpr float QSCALE = 0.125f * 1.4426950408889634f;

__device__ __forceinline__ u16 f2bf(float x){
  return __builtin_bit_cast(u16, __float2bfloat16(x));
}
__device__ __forceinline__ float bf2f(u16 u){
  return __builtin_bit_cast(float, (u32)u << 16);
}
__device__ __forceinline__ u16 f2h(float x){
  return __builtin_bit_cast(u16, (_Float16)x);
}
__device__ __forceinline__ u32 packh2(float a, float b){
  u16 x = __builtin_bit_cast(u16, (_Float16)a);
  u16 y = __builtin_bit_cast(u16, (_Float16)b);
  return (u32)x | ((u32)y << 16);
}
__device__ __forceinline__ float unph(u32 w, int hi){
  u16 u = hi ? (u16)(w >> 16) : (u16)(w & 0xffff);
  return (float)__builtin_bit_cast(_Float16, u);
}
__device__ __forceinline__ f32x4 mfma16(s16x8 a, s16x8 b, f32x4 c){
  return __builtin_amdgcn_mfma_f32_16x16x32_bf16(a, b, c, 0, 0, 0);
}
__device__ __forceinline__ f32x4 mfma16h(f16x8 a, f16x8 b, f32x4 c){
  return __builtin_amdgcn_mfma_f32_16x16x32_f16(a, b, c, 0, 0, 0);
}
__device__ __forceinline__ s16x8 ld8(const u16* p){
  return *reinterpret_cast<const s16x8*>(p);
}
__device__ __forceinline__ f16x8 ld8h(const u16* p){
  return *reinterpret_cast<const f16x8*>(p);
}
__device__ __forceinline__ void st_bf8(u16* p, float4 a, float4 b){
  s16x8 t;
  t[0] = (short)f2bf(a.x); t[1] = (short)f2bf(a.y);
  t[2] = (short)f2bf(a.z); t[3] = (short)f2bf(a.w);
  t[4] = (short)f2bf(b.x); t[5] = (short)f2bf(b.y);
  t[6] = (short)f2bf(b.z); t[7] = (short)f2bf(b.w);
  *reinterpret_cast<s16x8*>(p) = t;
}

// ---------------------------------------------------------------------------
// prep: rel_k -> bf16 [272][64]; rel_v -> FP16 transposed [64][288]
// ---------------------------------------------------------------------------
__global__ void prep_rel(const float* __restrict__ rel_k,
                         const float* __restrict__ rel_v,
                         u16* __restrict__ relkb, u16* __restrict__ relvT)
{
  int tid = blockIdx.x * blockDim.x + threadIdx.x;
  int nthr = gridDim.x * blockDim.x;
  for (int i = tid; i < RKROWS * DKc; i += nthr){
    int r = i >> 6, c = i & 63;
    float v = (r < NREL) ? rel_k[r * DKc + c] : 0.0f;
    relkb[i] = f2bf(v);
  }
  for (int i = tid; i < DKc * RVCOLS; i += nthr){
    int d = i / RVCOLS, j = i - d * RVCOLS;
    float v = (j < NREL) ? rel_v[j * DKc + d] : 0.0f;
    relvT[i] = f2h(v);
  }
}

// ---------------------------------------------------------------------------
// proj GEMM: C = X @ W^T + b -> bf16 Q (xQSCALE) / K ([bh][s][dk]); V^T in FP16
// ---------------------------------------------------------------------------
__global__ __launch_bounds__(256, 4) void proj_gemm(
    const float* __restrict__ Xq, const float* __restrict__ Xk, const float* __restrict__ Xv,
    const float* __restrict__ Wq, const float* __restrict__ Wk, const float* __restrict__ Wv,
    const float* __restrict__ bq, const float* __restrict__ bk, const float* __restrict__ bv,
    u16* __restrict__ Qb, u16* __restrict__ Kb, u16* __restrict__ Vt)
{
  const int type = blockIdx.y;
  const float* X    = (type == 0) ? Xq : (type == 1) ? Xk : Xv;
  const float* W    = (type == 0) ? Wq : (type == 1) ? Wk : Wv;
  const float* bias = (type == 0) ? bq : (type == 1) ? bk : bv;

  const int m0 = (int)(blockIdx.x >> 4) * 64;
  const int n0 = (int)(blockIdx.x & 15) * 64;

  __shared__ alignas(16) u16 As[64][56];
  __shared__ alignas(16) u16 Bs[64][56];

  const int tid  = threadIdx.x;
  const int wid  = tid >> 6, lane = tid & 63;
  const int lgrp = lane >> 4, lidx = lane & 15;
  const int wr   = wid >> 1,  wc   = wid & 1;

  const int srow = tid >> 2;
  const int scol = (tid & 3) << 3;

  f32x4 acc[2][2] = {};

  for (int it = 0; it < Dc / 32; ++it){
    const int k0 = it * 32;
    const float* xa = &X[(size_t)(m0 + srow) * Dc + k0 + scol];
    const float* xb = &W[(size_t)(n0 + srow) * Dc + k0 + scol];
    float4 a0 = *reinterpret_cast<const float4*>(xa);
    float4 a1 = *reinterpret_cast<const float4*>(xa + 4);
    float4 b0 = *reinterpret_cast<const float4*>(xb);
    float4 b1 = *reinterpret_cast<const float4*>(xb + 4);
    __syncthreads();
    st_bf8(&As[srow][scol], a0, a1);
    st_bf8(&Bs[srow][scol], b0, b1);
    __syncthreads();
    s16x8 af0 = ld8(&As[wr * 32 + lidx][lgrp * 8]);
    s16x8 af1 = ld8(&As[wr * 32 + 16 + lidx][lgrp * 8]);
    s16x8 bf0 = ld8(&Bs[wc * 32 + lidx][lgrp * 8]);
    s16x8 bf1 = ld8(&Bs[wc * 32 + 16 + lidx][lgrp * 8]);
    acc[0][0] = mfma16(af0, bf0, acc[0][0]);
    acc[0][1] = mfma16(af0, bf1, acc[0][1]);
    acc[1][0] = mfma16(af1, bf0, acc[1][0]);
    acc[1][1] = mfma16(af1, bf1, acc[1][1]);
  }

#pragma unroll
  for (int fm = 0; fm < 2; ++fm)
#pragma unroll
    for (int fn = 0; fn < 2; ++fn)
#pragma unroll
      for (int r = 0; r < 4; ++r){
        int mRow = m0 + wr * 32 + fm * 16 + lgrp * 4 + r;
        int nCol = n0 + wc * 32 + fn * 16 + lidx;
        float v = acc[fm][fn][r] + bias[nCol];
        int b = mRow >> 11, s = mRow & (Sc - 1);
        int h = nCol >> 6,  dk = nCol & 63;
        int bh = b * Hc + h;
        if (type == 0)      Qb[((size_t)bh * Sc + s) * DKc + dk] = f2bf(v * QSCALE);
        else if (type == 1) Kb[((size_t)bh * Sc + s) * DKc + dk] = f2bf(v);
        else                Vt[((size_t)bh * DKc + dk) * Sc + s] = f2h(v);
      }
}

// ---------------------------------------------------------------------------
// Fused attention -- SINGLE K-sweep.
//   WG = 512 thr / 8 waves; 16 q-rows per WG; each wave owns 256 k-columns.
//   Pass A: K loads + QK MFMA (permuted K-row feed -> p lane-local in PV
//   A-frag layout) + exp2 -> UNNORMALIZED pu kept packed fp16 in registers
//   (32 VGPRs) + PV MFMA (f16, unnormalized; cacc scaled by 1/l after).
//   Pass B: no loads -- unpack, normalize, nontemporal attn stores + band agg.
// ---------------------------------------------------------------------------
__global__ __launch_bounds__(512, 4) void attn_fused(
    const u16* __restrict__ Qb, const u16* __restrict__ Kb, const u16* __restrict__ Vt,
    const u16* __restrict__ relkb, const u16* __restrict__ relvT,
    float* __restrict__ attn_out, u16* __restrict__ ctxb)
{
  // smem: [0,8320) Rld | [8320,17536) Ag | [32768,33792) red
  // ctxS overlays [0,32768) after Ag is dead.
  __shared__ alignas(16) char smem[33792];
  u16 (*Rld)[260]       = reinterpret_cast<u16(*)[260]>(smem);            // bf16
  u16 (*Ag)[288]        = reinterpret_cast<u16(*)[288]>(smem + 8320);     // fp16
  float* red            = reinterpret_cast<float*>(smem + 32768);         // [2][8][16]
  float (*ctxS)[16][64] = reinterpret_cast<float(*)[16][64]>(smem);       // overlay

  const int tid  = threadIdx.x;
  const int wid  = tid >> 6, lane = tid & 63;
  const int lgrp = lane >> 4, lidx = lane & 15;

  // XCD-aware swizzle: 4096 WGs, 8 XCDs -> each XCD a contiguous 4-bh chunk
  const int flat    = (int)blockIdx.x;
  const int logical = (flat & 7) * 512 + (flat >> 3);
  const int bh      = logical >> 7;
  const int qtile   = logical & 127;
  const int q0      = qtile * 16;
  const int kbase   = wid * 256;          // 8 waves x 256 k

  const u16* Qp = Qb + (size_t)bh * Sc * DKc;
  const u16* Kp = Kb + (size_t)bh * Sc * DKc;
  const u16* Vp = Vt + (size_t)bh * DKc * Sc;
  float* attp   = attn_out + (size_t)bh * Sc * Sc;

  // Q fragments
  s16x8 aq0 = ld8(&Qp[(size_t)(q0 + lidx) * DKc + lgrp * 8]);
  s16x8 aq1 = ld8(&Qp[(size_t)(q0 + lidx) * DKc + 32 + lgrp * 8]);

  // R[q][j] = Q'[q] . rel_k[j]  (exp2-units), j-tiles split across 8 waves
  for (int jt = wid; jt < 17; jt += 8){
    int j0 = jt * 16;
    s16x8 b0 = ld8(&relkb[(size_t)(j0 + lidx) * DKc + lgrp * 8]);
    s16x8 b1 = ld8(&relkb[(size_t)(j0 + lidx) * DKc + 32 + lgrp * 8]);
    f32x4 rr = {0.f, 0.f, 0.f, 0.f};
    rr = mfma16(aq0, b0, rr);
    rr = mfma16(aq1, b1, rr);
    int j = j0 + lidx;
    if (j <= 256){
#pragma unroll
      for (int t = 0; t < 4; ++t) Rld[lgrp * 4 + t][j] = f2bf(rr[t]);
    }
  }
  { // zero Ag
    u32* agp = reinterpret_cast<u32*>(&Ag[0][0]);
    for (int i = tid; i < 16 * 288 / 2; i += 512) agp[i] = 0u;
  }
  __syncthreads();

  const float RloL = bf2f(Rld[lidx][0]);
  const float RhiL = bf2f(Rld[lidx][256]);

  // permuted K-row base offset (R4-verified feed)
  const int kperm = ((lidx >> 2) << 3) + (lidx & 3);

  u32 pw[8][4];               // packed fp16 unnormalized pu, all static-indexed
  f32x4 cacc[4] = {};
  float l = 0.f;

  // ---------------- PASS A: QK + exp2 + unnormalized PV ----------------
#pragma unroll
  for (int kb = 0; kb < 8; ++kb){
    const int kO = kbase + kb * 32;
    const bool all_lo = (kO + 31 - q0) <= -128;
    const bool all_hi = (kO - (q0 + 15)) >= 128;
    const u16* kr = &Kp[(size_t)(kO + kperm) * DKc];
    s16x8 bk00 = ld8(kr + lgrp * 8);
    s16x8 bk01 = ld8(kr + 32 + lgrp * 8);
    s16x8 bk10 = ld8(kr + 4 * DKc + lgrp * 8);
    s16x8 bk11 = ld8(kr + 4 * DKc + 32 + lgrp * 8);
    // V fragments for this k-block (fp16)
    f16x8 bv0 = ld8h(&Vp[(size_t)(0 * 16 + lidx) * Sc + kO + lgrp * 8]);
    f16x8 bv1 = ld8h(&Vp[(size_t)(1 * 16 + lidx) * Sc + kO + lgrp * 8]);
    f16x8 bv2 = ld8h(&Vp[(size_t)(2 * 16 + lidx) * Sc + kO + lgrp * 8]);
    f16x8 bv3 = ld8h(&Vp[(size_t)(3 * 16 + lidx) * Sc + kO + lgrp * 8]);

    f32x4 a0 = {0.f, 0.f, 0.f, 0.f}, a1 = {0.f, 0.f, 0.f, 0.f};
    a0 = mfma16(bk00, aq0, a0); a0 = mfma16(bk01, aq1, a0);
    a1 = mfma16(bk10, aq0, a1); a1 = mfma16(bk11, aq1, a1);

    float pu[8];
    if (all_lo | all_hi){
      const float addv = all_lo ? RloL : RhiL;
#pragma unroll
      for (int j = 0; j < 4; ++j){
        pu[j]     = __builtin_amdgcn_exp2f(a0[j] + addv);
        pu[j + 4] = __builtin_amdgcn_exp2f(a1[j] + addv);
      }
    } else {
      const int dd0 = kO + lgrp * 8 - (q0 + lidx);
#pragma unroll
      for (int j = 0; j < 8; ++j){
        int dd = dd0 + j;
        float add = (dd <= -128) ? RloL : (dd >= 128) ? RhiL : bf2f(Rld[lidx][dd + 128]);
        float av = (j < 4) ? a0[j] : a1[j - 4];
        pu[j] = __builtin_amdgcn_exp2f(av + add);
      }
    }
    l += ((pu[0] + pu[1]) + (pu[2] + pu[3])) + ((pu[4] + pu[5]) + (pu[6] + pu[7]));
    pw[kb][0] = packh2(pu[0], pu[1]);
    pw[kb][1] = packh2(pu[2], pu[3]);
    pw[kb][2] = packh2(pu[4], pu[5]);
    pw[kb][3] = packh2(pu[6], pu[7]);
    u32x4 apw = {pw[kb][0], pw[kb][1], pw[kb][2], pw[kb][3]};
    f16x8 ap = __builtin_bit_cast(f16x8, apw);
    cacc[0] = mfma16h(ap, bv0, cacc[0]);
    cacc[1] = mfma16h(ap, bv1, cacc[1]);
    cacc[2] = mfma16h(ap, bv2, cacc[2]);
    cacc[3] = mfma16h(ap, bv3, cacc[3]);
  }

  // reduce l across lgrp groups, then across 8 waves
  l += __shfl_xor(l, 16);
  l += __shfl_xor(l, 32);
  if (lane < 16) red[wid * 16 + lidx] = l;
  __syncthreads();
  float rscL, rsc4[4];
  {
    float s = 0.f;
#pragma unroll
    for (int w = 0; w < 8; ++w) s += red[w * 16 + lidx];
    rscL = 1.0f / s;
#pragma unroll
    for (int r = 0; r < 4; ++r){
      float t = 0.f;
#pragma unroll
      for (int w = 0; w < 8; ++w) t += red[w * 16 + lgrp * 4 + r];
      rsc4[r] = 1.0f / t;
    }
  }
  __syncthreads();   // red reused for border sums

  // normalize the PV partials (rows of cacc are q = lgrp*4 + r)
#pragma unroll
  for (int dg = 0; dg < 4; ++dg)
#pragma unroll
    for (int r = 0; r < 4; ++r) cacc[dg][r] *= rsc4[r];

  // ---------------- PASS B: normalize + stream attn + band agg ----------------
  float clow = 0.f, chigh = 0.f;
#pragma unroll
  for (int kb = 0; kb < 8; ++kb){
    const int kO = kbase + kb * 32;
    const bool all_lo = (kO + 31 - q0) <= -128;
    const bool all_hi = (kO - (q0 + 15)) >= 128;
    float p[8];
#pragma unroll
    for (int jj = 0; jj < 4; ++jj){
      p[2 * jj]     = unph(pw[kb][jj], 0) * rscL;
      p[2 * jj + 1] = unph(pw[kb][jj], 1) * rscL;
    }
    f32x4 p0 = {p[0], p[1], p[2], p[3]};
    f32x4 p1 = {p[4], p[5], p[6], p[7]};
    float* ap_out = &attp[(size_t)(q0 + lidx) * Sc + kO + lgrp * 8];
    __builtin_nontemporal_store(p0, reinterpret_cast<f32x4*>(ap_out));
    __builtin_nontemporal_store(p1, reinterpret_cast<f32x4*>(ap_out + 4));
    if (all_lo | all_hi){
      float ps = ((p[0] + p[1]) + (p[2] + p[3])) + ((p[4] + p[5]) + (p[6] + p[7]));
      if (all_lo) clow += ps; else chigh += ps;
    } else {
      const int dd0 = kO + lgrp * 8 - (q0 + lidx);
#pragma unroll
      for (int j = 0; j < 8; ++j){
        int dd = dd0 + j;
        if (dd <= -128)      clow  += p[j];
        else if (dd >= 128)  chigh += p[j];
        else                 Ag[lidx][dd + 128] = f2h(p[j]);
      }
    }
  }

  // fold border sums into Ag[q][0] / Ag[q][256]
  clow  += __shfl_xor(clow, 16);
  clow  += __shfl_xor(clow, 32);
  chigh += __shfl_xor(chigh, 16);
  chigh += __shfl_xor(chigh, 32);
  if (lane < 16){
    red[wid * 16 + lidx]       = clow;
    red[128 + wid * 16 + lidx] = chigh;
  }
  __syncthreads();
  if (tid < 16){
    float cl = 0.f, ch = 0.f;
#pragma unroll
    for (int w = 0; w < 8; ++w){
      cl += red[w * 16 + tid];
      ch += red[128 + w * 16 + tid];
    }
    Ag[tid][0]   = f2h(cl);
    Ag[tid][256] = f2h(ch);
  }
  __syncthreads();

  // ctx += Aagg @ rel_v  (9 j-steps split across 8 waves; fp16 MFMA)
  for (int t = wid; t < 9; t += 8){
    const int j0 = t * 32;
    f16x8 aa = ld8h(&Ag[lidx][j0 + lgrp * 8]);
#pragma unroll
    for (int dg = 0; dg < 4; ++dg){
      f16x8 bb = ld8h(&relvT[(size_t)(dg * 16 + lidx) * RVCOLS + j0 + lgrp * 8]);
      cacc[dg] = mfma16h(aa, bb, cacc[dg]);
    }
  }
  __syncthreads();   // Rld/Ag dead -> ctxS overlay valid

  // stage per-wave ctx partials (fp32), sum across 8 waves
#pragma unroll
  for (int dg = 0; dg < 4; ++dg)
#pragma unroll
    for (int r = 0; r < 4; ++r)
      ctxS[wid][lgrp * 4 + r][dg * 16 + lidx] = cacc[dg][r];
  __syncthreads();

  if (tid < 256){
    const int row2 = tid >> 4, qd = tid & 15;
    f32x4 sum = {0.f, 0.f, 0.f, 0.f};
#pragma unroll
    for (int w = 0; w < 8; ++w)
      sum += *reinterpret_cast<f32x4*>(&ctxS[w][row2][qd * 4]);
    const int b = bh >> 4, h = bh & 15;
    u16x4 o;
#pragma unroll
    for (int i = 0; i < 4; ++i) o[i] = f2bf(sum[i]);
    *reinterpret_cast<u16x4*>(&ctxb[((size_t)(b * Sc + q0 + row2)) * Dc + h * 64 + qd * 4]) = o;
  }
}

// ---------------------------------------------------------------------------
// out GEMM: out = ctx_bf16 @ Wo^T + bo (fp32)
// ---------------------------------------------------------------------------
__global__ __launch_bounds__(256, 4) void out_gemm(
    const u16* __restrict__ A, const float* __restrict__ W,
    const float* __restrict__ bias, float* __restrict__ out)
{
  const int m0 = (int)(blockIdx.x >> 4) * 64;
  const int n0 = (int)(blockIdx.x & 15) * 64;

  __shared__ alignas(16) u16 As[64][56];
  __shared__ alignas(16) u16 Bs[64][56];

  const int tid  = threadIdx.x;
  const int wid  = tid >> 6, lane = tid & 63;
  const int lgrp = lane >> 4, lidx = lane & 15;
  const int wr   = wid >> 1,  wc   = wid & 1;
  const int srow = tid >> 2;
  const int scol = (tid & 3) << 3;

  f32x4 acc[2][2] = {};

  for (int it = 0; it < Dc / 32; ++it){
    const int k0 = it * 32;
    s16x8 av = ld8(&A[(size_t)(m0 + srow) * Dc + k0 + scol]);
    const float* xb = &W[(size_t)(n0 + srow) * Dc + k0 + scol];
    float4 b0 = *reinterpret_cast<const float4*>(xb);
    float4 b1 = *reinterpret_cast<const float4*>(xb + 4);
    __syncthreads();
    *reinterpret_cast<s16x8*>(&As[srow][scol]) = av;
    st_bf8(&Bs[srow][scol], b0, b1);
    __syncthreads();
    s16x8 af0 = ld8(&As[wr * 32 + lidx][lgrp * 8]);
    s16x8 af1 = ld8(&As[wr * 32 + 16 + lidx][lgrp * 8]);
    s16x8 bf0 = ld8(&Bs[wc * 32 + lidx][lgrp * 8]);
    s16x8 bf1 = ld8(&Bs[wc * 32 + 16 + lidx][lgrp * 8]);
    acc[0][0] = mfma16(af0, bf0, acc[0][0]);
    acc[0][1] = mfma16(af0, bf1, acc[0][1]);
    acc[1][0] = mfma16(af1, bf0, acc[1][0]);
    acc[1][1] = mfma16(af1, bf1, acc[1][1]);
  }

#pragma unroll
  for (int fm = 0; fm < 2; ++fm)
#pragma unroll
    for (int fn = 0; fn < 2; ++fn)
#pragma unroll
      for (int r = 0; r < 4; ++r){
        int mRow = m0 + wr * 32 + fm * 16 + lgrp * 4 + r;
        int nCol = n0 + wc * 32 + fn * 16 + lidx;
        out[(size_t)mRow * Dc + nCol] = acc[fm][fn][r] + bias[nCol];
      }
}

// ---------------------------------------------------------------------------
extern "C" void kernel_launch(void* const* d_in, const int* in_sizes, int n_in,
                              void* d_out, int out_size, void* d_ws, size_t ws_size,
                              hipStream_t stream)
{
  const float* query = (const float*)d_in[0];
  const float* key_  = (const float*)d_in[1];
  const float* value = (const float*)d_in[2];
  const float* Wq    = (const float*)d_in[3];
  const float* bq    = (const float*)d_in[4];
  const float* Wk    = (const float*)d_in[5];
  const float* bk    = (const float*)d_in[6];
  const float* Wv    = (const float*)d_in[7];
  const float* bv    = (const float*)d_in[8];
  const float* Wo    = (const float*)d_in[9];
  const float* bo    = (const float*)d_in[10];
  const float* rel_k = (const float*)d_in[11];
  const float* rel_v = (const float*)d_in[12];

  float* outp  = (float*)d_out;
  float* attnp = outp + (size_t)Bc * Sc * Dc;

  u16* Qb    = (u16*)d_ws;
  u16* Kb    = Qb + (size_t)BHc * Sc * DKc;
  u16* Vt    = Kb + (size_t)BHc * Sc * DKc;          // fp16
  u16* ctxb  = Vt + (size_t)BHc * Sc * DKc;
  u16* relkb = ctxb + (size_t)Bc * Sc * Dc;
  u16* relvT = relkb + (size_t)RKROWS * DKc;         // fp16

  prep_rel<<<dim3(32), dim3(256), 0, stream>>>(rel_k, rel_v, relkb, relvT);
  proj_gemm<<<dim3((Bc * Sc / 64) * (Dc / 64), 3), dim3(256), 0, stream>>>(
      query, key_, value, Wq, Wk, Wv, bq, bk, bv, Qb, Kb, Vt);
  attn_fused<<<dim3((Sc / 16) * BHc), dim3(512), 0, stream>>>(
      Qb, Kb, Vt, relkb, relvT, attnp, ctxb);
  out_gemm<<<dim3((Bc * Sc / 64) * (Dc / 64)), dim3(256), 0, stream>>>(
      ctxb, Wo, bo, outp);
}

// Round 8
// 392.421 us; speedup vs baseline: 1.4081x; 1.4081x over previous
//
#include <hip/hip_runtime.h>
#include <hip/hip_bf16.h>
#include <cstdint>
#include <cstddef>

using u16 = unsigned short;
using u32 = unsigned int;

typedef float f32x4 __attribute__((ext_vector_type(4)));
typedef short s16x8 __attribute__((ext_vector_type(8)));
typedef _Float16 f16x8 __attribute__((ext_vector_type(8)));
typedef unsigned short u16x4 __attribute__((ext_vector_type(4)));
typedef u32 u32x4 __attribute__((ext_vector_type(4)));

constexpr int Bc  = 2;
constexpr int Sc  = 2048;
constexpr int Dc  = 1024;
constexpr int Hc  = 16;
constexpr int DKc = 64;
constexpr int BHc = Bc * Hc;        // 32
constexpr int NREL = 257;           // 2*128+1
constexpr int RKROWS = 272;         // rel_k rows padded to 17*16
constexpr int RVCOLS = 288;         // rel_v^T cols padded to 9*32

// scores in exp2-units: Q pre-scaled by 0.125*log2(e) at projection.
constexpr float QSCALE = 0.125f * 1.4426950408889634f;

__device__ __forceinline__ u16 f2bf(float x){
  return __builtin_bit_cast(u16, __float2bfloat16(x));
}
__device__ __forceinline__ float bf2f(u16 u){
  return __builtin_bit_cast(float, (u32)u << 16);
}
__device__ __forceinline__ u16 f2h(float x){
  return __builtin_bit_cast(u16, (_Float16)x);
}
__device__ __forceinline__ u32 packh2(float a, float b){
  u16 x = __builtin_bit_cast(u16, (_Float16)a);
  u16 y = __builtin_bit_cast(u16, (_Float16)b);
  return (u32)x | ((u32)y << 16);
}
__device__ __forceinline__ float h2f_lo(u32 w){
  return (float)__builtin_bit_cast(_Float16, (u16)(w & 0xffffu));
}
__device__ __forceinline__ float h2f_hi(u32 w){
  return (float)__builtin_bit_cast(_Float16, (u16)(w >> 16));
}
__device__ __forceinline__ f32x4 mfma16(s16x8 a, s16x8 b, f32x4 c){
  return __builtin_amdgcn_mfma_f32_16x16x32_bf16(a, b, c, 0, 0, 0);
}
__device__ __forceinline__ f32x4 mfma16h(f16x8 a, f16x8 b, f32x4 c){
  return __builtin_amdgcn_mfma_f32_16x16x32_f16(a, b, c, 0, 0, 0);
}
__device__ __forceinline__ s16x8 ld8(const u16* p){
  return *reinterpret_cast<const s16x8*>(p);
}
__device__ __forceinline__ f16x8 ld8h(const u16* p){
  return *reinterpret_cast<const f16x8*>(p);
}
__device__ __forceinline__ void st_bf8(u16* p, float4 a, float4 b){
  s16x8 t;
  t[0] = (short)f2bf(a.x); t[1] = (short)f2bf(a.y);
  t[2] = (short)f2bf(a.z); t[3] = (short)f2bf(a.w);
  t[4] = (short)f2bf(b.x); t[5] = (short)f2bf(b.y);
  t[6] = (short)f2bf(b.z); t[7] = (short)f2bf(b.w);
  *reinterpret_cast<s16x8*>(p) = t;
}

// ---------------------------------------------------------------------------
// prep: rel_k -> bf16 [272][64]; rel_v -> FP16 transposed [64][288]
// ---------------------------------------------------------------------------
__global__ void prep_rel(const float* __restrict__ rel_k,
                         const float* __restrict__ rel_v,
                         u16* __restrict__ relkb, u16* __restrict__ relvT)
{
  int tid = blockIdx.x * blockDim.x + threadIdx.x;
  int nthr = gridDim.x * blockDim.x;
  for (int i = tid; i < RKROWS * DKc; i += nthr){
    int r = i >> 6, c = i & 63;
    float v = (r < NREL) ? rel_k[r * DKc + c] : 0.0f;
    relkb[i] = f2bf(v);
  }
  for (int i = tid; i < DKc * RVCOLS; i += nthr){
    int d = i / RVCOLS, j = i - d * RVCOLS;
    float v = (j < NREL) ? rel_v[j * DKc + d] : 0.0f;
    relvT[i] = f2h(v);
  }
}

// ---------------------------------------------------------------------------
// proj GEMM: C = X @ W^T + b -> bf16 Q (xQSCALE) / K ([bh][s][dk]); V^T in FP16
// ---------------------------------------------------------------------------
__global__ __launch_bounds__(256, 4) void proj_gemm(
    const float* __restrict__ Xq, const float* __restrict__ Xk, const float* __restrict__ Xv,
    const float* __restrict__ Wq, const float* __restrict__ Wk, const float* __restrict__ Wv,
    const float* __restrict__ bq, const float* __restrict__ bk, const float* __restrict__ bv,
    u16* __restrict__ Qb, u16* __restrict__ Kb, u16* __restrict__ Vt)
{
  const int type = blockIdx.y;
  const float* X    = (type == 0) ? Xq : (type == 1) ? Xk : Xv;
  const float* W    = (type == 0) ? Wq : (type == 1) ? Wk : Wv;
  const float* bias = (type == 0) ? bq : (type == 1) ? bk : bv;

  const int m0 = (int)(blockIdx.x >> 4) * 64;
  const int n0 = (int)(blockIdx.x & 15) * 64;

  __shared__ alignas(16) u16 As[64][56];
  __shared__ alignas(16) u16 Bs[64][56];

  const int tid  = threadIdx.x;
  const int wid  = tid >> 6, lane = tid & 63;
  const int lgrp = lane >> 4, lidx = lane & 15;
  const int wr   = wid >> 1,  wc   = wid & 1;

  const int srow = tid >> 2;
  const int scol = (tid & 3) << 3;

  f32x4 acc[2][2] = {};

  for (int it = 0; it < Dc / 32; ++it){
    const int k0 = it * 32;
    const float* xa = &X[(size_t)(m0 + srow) * Dc + k0 + scol];
    const float* xb = &W[(size_t)(n0 + srow) * Dc + k0 + scol];
    float4 a0 = *reinterpret_cast<const float4*>(xa);
    float4 a1 = *reinterpret_cast<const float4*>(xa + 4);
    float4 b0 = *reinterpret_cast<const float4*>(xb);
    float4 b1 = *reinterpret_cast<const float4*>(xb + 4);
    __syncthreads();
    st_bf8(&As[srow][scol], a0, a1);
    st_bf8(&Bs[srow][scol], b0, b1);
    __syncthreads();
    s16x8 af0 = ld8(&As[wr * 32 + lidx][lgrp * 8]);
    s16x8 af1 = ld8(&As[wr * 32 + 16 + lidx][lgrp * 8]);
    s16x8 bf0 = ld8(&Bs[wc * 32 + lidx][lgrp * 8]);
    s16x8 bf1 = ld8(&Bs[wc * 32 + 16 + lidx][lgrp * 8]);
    acc[0][0] = mfma16(af0, bf0, acc[0][0]);
    acc[0][1] = mfma16(af0, bf1, acc[0][1]);
    acc[1][0] = mfma16(af1, bf0, acc[1][0]);
    acc[1][1] = mfma16(af1, bf1, acc[1][1]);
  }

#pragma unroll
  for (int fm = 0; fm < 2; ++fm)
#pragma unroll
    for (int fn = 0; fn < 2; ++fn)
#pragma unroll
      for (int r = 0; r < 4; ++r){
        int mRow = m0 + wr * 32 + fm * 16 + lgrp * 4 + r;
        int nCol = n0 + wc * 32 + fn * 16 + lidx;
        float v = acc[fm][fn][r] + bias[nCol];
        int b = mRow >> 11, s = mRow & (Sc - 1);
        int h = nCol >> 6,  dk = nCol & 63;
        int bh = b * Hc + h;
        if (type == 0)      Qb[((size_t)bh * Sc + s) * DKc + dk] = f2bf(v * QSCALE);
        else if (type == 1) Kb[((size_t)bh * Sc + s) * DKc + dk] = f2bf(v);
        else                Vt[((size_t)bh * DKc + dk) * Sc + s] = f2h(v);
      }
}

// ---------------------------------------------------------------------------
// Fused attention -- single K-sweep + coalesced stream-out.
//   Identical to R7 except the stream-out LDS read-back: same-type (u32)
//   accesses + compiler memory fences so the write->read->next-write order
//   cannot be broken by TBAA-based reordering (R7's attn corruption).
// ---------------------------------------------------------------------------
__global__ __launch_bounds__(512, 4) void attn_fused(
    const u16* __restrict__ Qb, const u16* __restrict__ Kb, const u16* __restrict__ Vt,
    const u16* __restrict__ relkb, const u16* __restrict__ relvT,
    float* __restrict__ attn_out, u16* __restrict__ ctxb)
{
  // [0,32768) Pw (8 waves x 16 rows x 64 u32, swizzled) | ctxS overlay
  // [32768,41088) Rld | [41088,50304) Ag | [50304,51840) red | [51840,51904) rscRow
  __shared__ alignas(16) char smem[51904];
  u32*  Pw        = reinterpret_cast<u32*>(smem);
  u16 (*Rld)[260] = reinterpret_cast<u16(*)[260]>(smem + 32768);
  u16 (*Ag)[288]  = reinterpret_cast<u16(*)[288]>(smem + 41088);
  float* red      = reinterpret_cast<float*>(smem + 50304);   // [3][128]
  float* rscRow   = reinterpret_cast<float*>(smem + 51840);   // [16]
  float (*ctxS)[16][64] = reinterpret_cast<float(*)[16][64]>(smem);

  const int tid  = threadIdx.x;
  const int wid  = tid >> 6, lane = tid & 63;
  const int lgrp = lane >> 4, lidx = lane & 15;

  // XCD-aware swizzle: 4096 WGs, 8 XCDs
  const int flat    = (int)blockIdx.x;
  const int logical = (flat & 7) * 512 + (flat >> 3);
  const int bh      = logical >> 7;
  const int qtile   = logical & 127;
  const int q0      = qtile * 16;
  const int kbase   = wid * 256;          // 8 waves x 256 k

  const u16* Qp = Qb + (size_t)bh * Sc * DKc;
  const u16* Kp = Kb + (size_t)bh * Sc * DKc;
  const u16* Vp = Vt + (size_t)bh * DKc * Sc;
  float* attp   = attn_out + (size_t)bh * Sc * Sc;

  // Q fragments
  s16x8 aq0 = ld8(&Qp[(size_t)(q0 + lidx) * DKc + lgrp * 8]);
  s16x8 aq1 = ld8(&Qp[(size_t)(q0 + lidx) * DKc + 32 + lgrp * 8]);

  // R[q][j] = Q'[q] . rel_k[j]  (exp2-units), split across 8 waves
  for (int jt = wid; jt < 17; jt += 8){
    int j0 = jt * 16;
    s16x8 b0 = ld8(&relkb[(size_t)(j0 + lidx) * DKc + lgrp * 8]);
    s16x8 b1 = ld8(&relkb[(size_t)(j0 + lidx) * DKc + 32 + lgrp * 8]);
    f32x4 rr = {0.f, 0.f, 0.f, 0.f};
    rr = mfma16(aq0, b0, rr);
    rr = mfma16(aq1, b1, rr);
    int j = j0 + lidx;
    if (j <= 256){
#pragma unroll
      for (int t = 0; t < 4; ++t) Rld[lgrp * 4 + t][j] = f2bf(rr[t]);
    }
  }
  { // zero Ag
    u32* agp = reinterpret_cast<u32*>(&Ag[0][0]);
    for (int i = tid; i < 16 * 288 / 2; i += 512) agp[i] = 0u;
  }
  __syncthreads();

  const float RloL = bf2f(Rld[lidx][0]);
  const float RhiL = bf2f(Rld[lidx][256]);
  const int kperm = ((lidx >> 2) << 3) + (lidx & 3);

  u32x4 pw[8];                 // packed fp16 UNNORMALIZED pu
  f32x4 cacc[4] = {};
  float l = 0.f, clow = 0.f, chigh = 0.f;

  // ---------------- PASS A: QK + exp2 + unnormalized PV + band agg ----------
#pragma unroll
  for (int kb = 0; kb < 8; ++kb){
    const int kO = kbase + kb * 32;
    const bool all_lo = (kO + 31 - q0) <= -128;
    const bool all_hi = (kO - (q0 + 15)) >= 128;
    const u16* kr = &Kp[(size_t)(kO + kperm) * DKc];
    s16x8 bk00 = ld8(kr + lgrp * 8);
    s16x8 bk01 = ld8(kr + 32 + lgrp * 8);
    s16x8 bk10 = ld8(kr + 4 * DKc + lgrp * 8);
    s16x8 bk11 = ld8(kr + 4 * DKc + 32 + lgrp * 8);
    f16x8 bv0 = ld8h(&Vp[(size_t)(lidx) * Sc + kO + lgrp * 8]);
    f16x8 bv1 = ld8h(&Vp[(size_t)(16 + lidx) * Sc + kO + lgrp * 8]);
    f16x8 bv2 = ld8h(&Vp[(size_t)(32 + lidx) * Sc + kO + lgrp * 8]);
    f16x8 bv3 = ld8h(&Vp[(size_t)(48 + lidx) * Sc + kO + lgrp * 8]);

    f32x4 a0 = {0.f, 0.f, 0.f, 0.f}, a1 = {0.f, 0.f, 0.f, 0.f};
    a0 = mfma16(bk00, aq0, a0); a0 = mfma16(bk01, aq1, a0);
    a1 = mfma16(bk10, aq0, a1); a1 = mfma16(bk11, aq1, a1);

    float pu[8];
    if (all_lo | all_hi){
      const float addv = all_lo ? RloL : RhiL;
#pragma unroll
      for (int j = 0; j < 4; ++j){
        pu[j]     = __builtin_amdgcn_exp2f(a0[j] + addv);
        pu[j + 4] = __builtin_amdgcn_exp2f(a1[j] + addv);
      }
      float ps = ((pu[0] + pu[1]) + (pu[2] + pu[3])) + ((pu[4] + pu[5]) + (pu[6] + pu[7]));
      if (all_lo) clow += ps; else chigh += ps;
      l += ps;
    } else {
      const int dd0 = kO + lgrp * 8 - (q0 + lidx);
#pragma unroll
      for (int j = 0; j < 8; ++j){
        int dd = dd0 + j;
        float add = (dd <= -128) ? RloL : (dd >= 128) ? RhiL : bf2f(Rld[lidx][dd + 128]);
        float av = (j < 4) ? a0[j] : a1[j - 4];
        float p = __builtin_amdgcn_exp2f(av + add);
        pu[j] = p;
        if (dd <= -128)      clow  += p;
        else if (dd >= 128)  chigh += p;
        else                 Ag[lidx][dd + 128] = f2h(p);   // unnormalized
      }
      l += ((pu[0] + pu[1]) + (pu[2] + pu[3])) + ((pu[4] + pu[5]) + (pu[6] + pu[7]));
    }
    u32x4 w4 = {packh2(pu[0], pu[1]), packh2(pu[2], pu[3]),
                packh2(pu[4], pu[5]), packh2(pu[6], pu[7])};
    pw[kb] = w4;
    f16x8 ap = __builtin_bit_cast(f16x8, w4);
    cacc[0] = mfma16h(ap, bv0, cacc[0]);
    cacc[1] = mfma16h(ap, bv1, cacc[1]);
    cacc[2] = mfma16h(ap, bv2, cacc[2]);
    cacc[3] = mfma16h(ap, bv3, cacc[3]);
  }

  // ---------------- reduce l and borders ----------------
  l     += __shfl_xor(l, 16);      l     += __shfl_xor(l, 32);
  clow  += __shfl_xor(clow, 16);   clow  += __shfl_xor(clow, 32);
  chigh += __shfl_xor(chigh, 16);  chigh += __shfl_xor(chigh, 32);
  if (lane < 16){
    red[wid * 16 + lidx]       = l;
    red[128 + wid * 16 + lidx] = clow;
    red[256 + wid * 16 + lidx] = chigh;
  }
  __syncthreads();
  if (tid < 16){
    float s = 0.f, cl = 0.f, ch = 0.f;
#pragma unroll
    for (int w = 0; w < 8; ++w){
      s  += red[w * 16 + tid];
      cl += red[128 + w * 16 + tid];
      ch += red[256 + w * 16 + tid];
    }
    rscRow[tid] = 1.0f / s;
    Ag[tid][0]   = f2h(cl);       // unnormalized borders
    Ag[tid][256] = f2h(ch);
  }
  __syncthreads();

  // ------- stream-out: pw -> swizzled per-wave LDS -> full-line NT stores ---
  // Per half h (128 k): tile = 16 rows x 64 u32; physical col = logical ^
  // ((row&7)<<2). Same-type u32 accesses + compiler fences keep write->read
  // ordering (TBAA-safe); per-wave in-order LDS pipe gives HW ordering.
  {
    u32* PwW = Pw + wid * 1024;
    const int xsw = (lidx & 7) << 2;
#pragma unroll
    for (int h = 0; h < 2; ++h){
#pragma unroll
      for (int kb4 = 0; kb4 < 4; ++kb4){
        int csw = (kb4 * 16 + lgrp * 4) ^ xsw;
        *reinterpret_cast<u32x4*>(&PwW[lidx * 64 + csw]) = pw[h * 4 + kb4];
      }
      __asm__ volatile("" ::: "memory");   // order: writes before reads
#pragma unroll
      for (int rr = 0; rr < 8; ++rr){
        const int row = rr * 2 + (lane >> 5);          // 0..15
        const int cc  = ((lane & 31) * 2) ^ ((row & 7) << 2);
        u32 w0 = PwW[row * 64 + cc];
        u32 w1 = PwW[row * 64 + cc + 1];
        float sc_ = rscRow[row];
        f32x4 o;
        o[0] = h2f_lo(w0) * sc_;
        o[1] = h2f_hi(w0) * sc_;
        o[2] = h2f_lo(w1) * sc_;
        o[3] = h2f_hi(w1) * sc_;
        __builtin_nontemporal_store(o, reinterpret_cast<f32x4*>(
            &attp[(size_t)(q0 + row) * Sc + kbase + h * 128 + (lane & 31) * 4]));
      }
      __asm__ volatile("" ::: "memory");   // order: reads before next writes
    }
  }

  // ---------------- ctx += Aagg @ rel_v (unnormalized), then normalize -----
  for (int t = wid; t < 9; t += 8){
    const int j0 = t * 32;
    f16x8 aa = ld8h(&Ag[lidx][j0 + lgrp * 8]);
#pragma unroll
    for (int dg = 0; dg < 4; ++dg){
      f16x8 bb = ld8h(&relvT[(size_t)(dg * 16 + lidx) * RVCOLS + j0 + lgrp * 8]);
      cacc[dg] = mfma16h(aa, bb, cacc[dg]);
    }
  }
#pragma unroll
  for (int dg = 0; dg < 4; ++dg)
#pragma unroll
    for (int r = 0; r < 4; ++r) cacc[dg][r] *= rscRow[lgrp * 4 + r];

  __syncthreads();   // all Pw reads done -> ctxS overlay valid

#pragma unroll
  for (int dg = 0; dg < 4; ++dg)
#pragma unroll
    for (int r = 0; r < 4; ++r)
      ctxS[wid][lgrp * 4 + r][dg * 16 + lidx] = cacc[dg][r];
  __syncthreads();

  if (tid < 256){
    const int row2 = tid >> 4, qd = tid & 15;
    f32x4 sum = {0.f, 0.f, 0.f, 0.f};
#pragma unroll
    for (int w = 0; w < 8; ++w)
      sum += *reinterpret_cast<f32x4*>(&ctxS[w][row2][qd * 4]);
    const int b = bh >> 4, h = bh & 15;
    u16x4 o;
#pragma unroll
    for (int i = 0; i < 4; ++i) o[i] = f2bf(sum[i]);
    *reinterpret_cast<u16x4*>(&ctxb[((size_t)(b * Sc + q0 + row2)) * Dc + h * 64 + qd * 4]) = o;
  }
}

// ---------------------------------------------------------------------------
// out GEMM: out = ctx_bf16 @ Wo^T + bo (fp32)
// ---------------------------------------------------------------------------
__global__ __launch_bounds__(256, 4) void out_gemm(
    const u16* __restrict__ A, const float* __restrict__ W,
    const float* __restrict__ bias, float* __restrict__ out)
{
  const int m0 = (int)(blockIdx.x >> 4) * 64;
  const int n0 = (int)(blockIdx.x & 15) * 64;

  __shared__ alignas(16) u16 As[64][56];
  __shared__ alignas(16) u16 Bs[64][56];

  const int tid  = threadIdx.x;
  const int wid  = tid >> 6, lane = tid & 63;
  const int lgrp = lane >> 4, lidx = lane & 15;
  const int wr   = wid >> 1,  wc   = wid & 1;
  const int srow = tid >> 2;
  const int scol = (tid & 3) << 3;

  f32x4 acc[2][2] = {};

  for (int it = 0; it < Dc / 32; ++it){
    const int k0 = it * 32;
    s16x8 av = ld8(&A[(size_t)(m0 + srow) * Dc + k0 + scol]);
    const float* xb = &W[(size_t)(n0 + srow) * Dc + k0 + scol];
    float4 b0 = *reinterpret_cast<const float4*>(xb);
    float4 b1 = *reinterpret_cast<const float4*>(xb + 4);
    __syncthreads();
    *reinterpret_cast<s16x8*>(&As[srow][scol]) = av;
    st_bf8(&Bs[srow][scol], b0, b1);
    __syncthreads();
    s16x8 af0 = ld8(&As[wr * 32 + lidx][lgrp * 8]);
    s16x8 af1 = ld8(&As[wr * 32 + 16 + lidx][lgrp * 8]);
    s16x8 bf0 = ld8(&Bs[wc * 32 + lidx][lgrp * 8]);
    s16x8 bf1 = ld8(&Bs[wc * 32 + 16 + lidx][lgrp * 8]);
    acc[0][0] = mfma16(af0, bf0, acc[0][0]);
    acc[0][1] = mfma16(af0, bf1, acc[0][1]);
    acc[1][0] = mfma16(af1, bf0, acc[1][0]);
    acc[1][1] = mfma16(af1, bf1, acc[1][1]);
  }

#pragma unroll
  for (int fm = 0; fm < 2; ++fm)
#pragma unroll
    for (int fn = 0; fn < 2; ++fn)
#pragma unroll
      for (int r = 0; r < 4; ++r){
        int mRow = m0 + wr * 32 + fm * 16 + lgrp * 4 + r;
        int nCol = n0 + wc * 32 + fn * 16 + lidx;
        out[(size_t)mRow * Dc + nCol] = acc[fm][fn][r] + bias[nCol];
      }
}

// ---------------------------------------------------------------------------
extern "C" void kernel_launch(void* const* d_in, const int* in_sizes, int n_in,
                              void* d_out, int out_size, void* d_ws, size_t ws_size,
                              hipStream_t stream)
{
  const float* query = (const float*)d_in[0];
  const float* key_  = (const float*)d_in[1];
  const float* value = (const float*)d_in[2];
  const float* Wq    = (const float*)d_in[3];
  const float* bq    = (const float*)d_in[4];
  const float* Wk    = (const float*)d_in[5];
  const float* bk    = (const float*)d_in[6];
  const float* Wv    = (const float*)d_in[7];
  const float* bv    = (const float*)d_in[8];
  const float* Wo    = (const float*)d_in[9];
  const float* bo    = (const float*)d_in[10];
  const float* rel_k = (const float*)d_in[11];
  const float* rel_v = (const float*)d_in[12];

  float* outp  = (float*)d_out;
  float* attnp = outp + (size_t)Bc * Sc * Dc;

  u16* Qb    = (u16*)d_ws;
  u16* Kb    = Qb + (size_t)BHc * Sc * DKc;
  u16* Vt    = Kb + (size_t)BHc * Sc * DKc;          // fp16
  u16* ctxb  = Vt + (size_t)BHc * Sc * DKc;
  u16* relkb = ctxb + (size_t)Bc * Sc * Dc;
  u16* relvT = relkb + (size_t)RKROWS * DKc;         // fp16

  prep_rel<<<dim3(32), dim3(256), 0, stream>>>(rel_k, rel_v, relkb, relvT);
  proj_gemm<<<dim3((Bc * Sc / 64) * (Dc / 64), 3), dim3(256), 0, stream>>>(
      query, key_, value, Wq, Wk, Wv, bq, bk, bv, Qb, Kb, Vt);
  attn_fused<<<dim3((Sc / 16) * BHc), dim3(512), 0, stream>>>(
      Qb, Kb, Vt, relkb, relvT, attnp, ctxb);
  out_gemm<<<dim3((Bc * Sc / 64) * (Dc / 64)), dim3(256), 0, stream>>>(
      ctxb, Wo, bo, outp);
}